// Round 3
// baseline (934.404 us; speedup 1.0000x reference)
//
#include <hip/hip_runtime.h>
#include <hip/hip_bf16.h>
#include <stdint.h>

#define F 256            // IN_F == OUT_F == 256
#define KSTEP 32

typedef short bhalf8 __attribute__((ext_vector_type(8)));
typedef unsigned short ushort8v __attribute__((ext_vector_type(8)));
typedef float f32x4 __attribute__((ext_vector_type(4)));
typedef int i32x4 __attribute__((ext_vector_type(4)));

__device__ __forceinline__ unsigned short f2b(float f) {
    union { float f; uint32_t u; } x; x.f = f;
    uint32_t u = x.u;
    return (unsigned short)((u + 0x7FFFu + ((u >> 16) & 1u)) >> 16);
}
__device__ __forceinline__ float b2f(unsigned short h) {
    union { uint32_t u; float f; } x; x.u = ((uint32_t)h) << 16;
    return x.f;
}

// ---------------------------------------------------------------------------
// W prep: f32 W[k][n] -> bf16, pre-tiled per K-step in the exact LDS staging
// image: Wt[sel][ks][n][kk]  (sel: 0=mean 1=var)
// ---------------------------------------------------------------------------
__global__ __launch_bounds__(256) void wprep_kernel(
    const float* __restrict__ Wm, const float* __restrict__ Wv,
    unsigned short* __restrict__ Wt)
{
    int idx = blockIdx.x * 256 + threadIdx.x;   // 4096 = 2 sel * 8 ks * 256 n
    int sel = idx >> 11;
    int ks  = (idx >> 8) & 7;
    int n   = idx & 255;
    const float* W = sel ? Wv : Wm;
    unsigned short* dst = Wt + ((size_t)sel * 8 * 256 * 32) + ((size_t)(ks * 256 + n) * 32);
    #pragma unroll
    for (int kk = 0; kk < 32; ++kk)
        dst[kk] = f2b(W[(ks * 32 + kk) * 256 + n]);
}

// ---------------------------------------------------------------------------
// Dense: m' = elu(mean@Wm + bm) * att ;  v' = relu(var@Wv + bv) * att^2
// att = exp(-relu(var@Wv+bv)). Stored bf16 INTERLEAVED: mv[row][512].
// 64 rows x 256 cols per block, 8 waves. A inputs NT-loaded (read-once).
// ---------------------------------------------------------------------------
__global__ __launch_bounds__(512) void dense_kernel(
    const float* __restrict__ mean, const float* __restrict__ var,
    const unsigned short* __restrict__ Wt,
    const float* __restrict__ bm, const float* __restrict__ bv,
    unsigned short* __restrict__ mv, int N)
{
    __shared__ unsigned short Asm[64][40];
    __shared__ unsigned short Asv[64][40];
    __shared__ unsigned short Bsm[256][40];
    __shared__ unsigned short Bsv[256][40];

    const int tid  = threadIdx.x;
    const int row0 = blockIdx.x * 64;
    const int lane = tid & 63;
    const int w    = tid >> 6;
    const int wr   = w >> 2;
    const int wc   = w & 3;
    const int lr   = lane & 15;
    const int lk   = lane >> 4;

    f32x4 accm[2][4], accv[2][4];
    #pragma unroll
    for (int i = 0; i < 2; ++i)
        #pragma unroll
        for (int j = 0; j < 4; ++j) { accm[i][j] = (f32x4)0.f; accv[i][j] = (f32x4)0.f; }

    const int srow = tid >> 3;
    const int skq  = (tid & 7) * 4;
    int sgrow = row0 + srow; if (sgrow >= N) sgrow = N - 1;

    const unsigned short* WtV = Wt + (size_t)8 * 256 * 32;

    for (int ks = 0; ks < F / KSTEP; ++ks) {
        const int k0 = ks * KSTEP;
        // stage A (f32 -> bf16), NT (read-once stream)
        {
            f32x4 am = __builtin_nontemporal_load((const f32x4*)&mean[(size_t)sgrow * F + k0 + skq]);
            f32x4 av = __builtin_nontemporal_load((const f32x4*)&var [(size_t)sgrow * F + k0 + skq]);
            ushort4 um = { f2b(am[0]), f2b(am[1]), f2b(am[2]), f2b(am[3]) };
            ushort4 uv = { f2b(av[0]), f2b(av[1]), f2b(av[2]), f2b(av[3]) };
            *(ushort4*)&Asm[srow][skq] = um;
            *(ushort4*)&Asv[srow][skq] = uv;
        }
        // stage B: flat coalesced copy of the pre-tiled 16KB slice (x2)
        {
            const unsigned short* sm = Wt  + (size_t)(ks * 256) * 32;
            const unsigned short* sv = WtV + (size_t)(ks * 256) * 32;
            #pragma unroll
            for (int h = 0; h < 2; ++h) {
                int c = tid + h * 512;
                int n = c >> 2, q = c & 3;
                *(ushort8v*)&Bsm[n][q * 8] = *(const ushort8v*)(sm + (size_t)n * 32 + q * 8);
                *(ushort8v*)&Bsv[n][q * 8] = *(const ushort8v*)(sv + (size_t)n * 32 + q * 8);
            }
        }
        __syncthreads();

        bhalf8 am0 = *(const bhalf8*)&Asm[wr*32 +  0 + lr][lk*8];
        bhalf8 am1 = *(const bhalf8*)&Asm[wr*32 + 16 + lr][lk*8];
        bhalf8 av0 = *(const bhalf8*)&Asv[wr*32 +  0 + lr][lk*8];
        bhalf8 av1 = *(const bhalf8*)&Asv[wr*32 + 16 + lr][lk*8];
        #pragma unroll
        for (int ct = 0; ct < 4; ++ct) {
            bhalf8 bmf = *(const bhalf8*)&Bsm[wc*64 + ct*16 + lr][lk*8];
            bhalf8 bvf = *(const bhalf8*)&Bsv[wc*64 + ct*16 + lr][lk*8];
            accm[0][ct] = __builtin_amdgcn_mfma_f32_16x16x32_bf16(am0, bmf, accm[0][ct], 0, 0, 0);
            accm[1][ct] = __builtin_amdgcn_mfma_f32_16x16x32_bf16(am1, bmf, accm[1][ct], 0, 0, 0);
            accv[0][ct] = __builtin_amdgcn_mfma_f32_16x16x32_bf16(av0, bvf, accv[0][ct], 0, 0, 0);
            accv[1][ct] = __builtin_amdgcn_mfma_f32_16x16x32_bf16(av1, bvf, accv[1][ct], 0, 0, 0);
        }
        __syncthreads();
    }

    #pragma unroll
    for (int rt = 0; rt < 2; ++rt) {
        #pragma unroll
        for (int ct = 0; ct < 4; ++ct) {
            const int col = wc*64 + ct*16 + lr;
            const float bmc = bm[col], bvc = bv[col];
            #pragma unroll
            for (int q = 0; q < 4; ++q) {
                int grow = row0 + wr*32 + rt*16 + lk*4 + q;
                if (grow < N) {
                    float mp = accm[rt][ct][q] + bmc;
                    float vp = accv[rt][ct][q] + bvc;
                    float me = mp > 0.f ? mp : (__expf(mp) - 1.f);
                    float vr = vp > 0.f ? vp : 0.f;
                    float att = __expf(-vr);
                    mv[(size_t)grow * 512 + col]       = f2b(me * att);
                    mv[(size_t)grow * 512 + 256 + col] = f2b(vr * att * att);
                }
            }
        }
    }
}

// ---------------------------------------------------------------------------
// CSR build (runs BEFORE dense so its streams don't evict mv from L3)
// ---------------------------------------------------------------------------
__global__ void hist_kernel(const int* __restrict__ row, int E, int* __restrict__ count) {
    int i = blockIdx.x * blockDim.x + threadIdx.x;
    if (i < E) {
        int r = __builtin_nontemporal_load(&row[i]);
        atomicAdd(&count[r], 1);
    }
}

__global__ __launch_bounds__(256) void scan1_kernel(const int* __restrict__ count, int N,
                                                    int* __restrict__ offs, int* __restrict__ bsums)
{
    __shared__ int sd[256];
    int t  = threadIdx.x;
    int gi = blockIdx.x * 1024 + t * 4;
    int c[4];
    #pragma unroll
    for (int q = 0; q < 4; ++q) c[q] = (gi + q < N) ? count[gi + q] : 0;
    int s = c[0] + c[1] + c[2] + c[3];
    sd[t] = s; __syncthreads();
    int acc = s;
    for (int off = 1; off < 256; off <<= 1) {
        int u = (t >= off) ? sd[t - off] : 0;
        __syncthreads();
        acc += u; sd[t] = acc;
        __syncthreads();
    }
    int run = acc - s;
    #pragma unroll
    for (int q = 0; q < 4; ++q) { if (gi + q < N) offs[gi + q] = run; run += c[q]; }
    if (t == 255) bsums[blockIdx.x] = acc;
}

__global__ __launch_bounds__(128) void scan2_kernel(int* __restrict__ bsums, int SB,
                                                    int* __restrict__ offs, int N)
{
    __shared__ int sd[128];
    int t = threadIdx.x;
    int v = (t < SB) ? bsums[t] : 0;
    sd[t] = v; __syncthreads();
    int acc = v;
    for (int off = 1; off < 128; off <<= 1) {
        int u = (t >= off) ? sd[t - off] : 0;
        __syncthreads();
        acc += u; sd[t] = acc;
        __syncthreads();
    }
    if (t < SB) bsums[t] = acc - v;
    if (t == 127) offs[N] = sd[127];
}

__global__ __launch_bounds__(256) void scan3_kernel(int* __restrict__ offs, int N,
                                                    const int* __restrict__ bsums)
{
    int b  = bsums[blockIdx.x];
    int gi = blockIdx.x * 1024 + threadIdx.x * 4;
    #pragma unroll
    for (int q = 0; q < 4; ++q) if (gi + q < N) offs[gi + q] += b;
}

__global__ void fill_kernel(const int* __restrict__ row, const int* __restrict__ col,
                            const float* __restrict__ a0, const float* __restrict__ a1,
                            int E, int* __restrict__ cursor, i32x4* __restrict__ rec)
{
    int i = blockIdx.x * blockDim.x + threadIdx.x;
    if (i < E) {
        int   r  = __builtin_nontemporal_load(&row[i]);
        int   c  = __builtin_nontemporal_load(&col[i]);
        float v0 = __builtin_nontemporal_load(&a0[i]);
        float v1 = __builtin_nontemporal_load(&a1[i]);
        int pos = atomicAdd(&cursor[r], 1);
        i32x4 rc;
        rc[0] = c;
        rc[1] = __float_as_int(v0);
        rc[2] = __float_as_int(v1);
        rc[3] = 0;
        rec[pos] = rc;   // normal store: L2 write-allocate coalesces sibling records
    }
}

// ---------------------------------------------------------------------------
// Fused SpMM: 1 wave per node; per edge one NT record load + one 16B gather
// (lanes 0-31: m half, lanes 32-63: v half). Output NT-stored (write-once)
// so mv stays resident in L3.
// ---------------------------------------------------------------------------
__global__ __launch_bounds__(256) void spmm_kernel(
    const int* __restrict__ offs, const i32x4* __restrict__ rec,
    const unsigned short* __restrict__ mv,
    float* __restrict__ out, int N)
{
    int w    = threadIdx.x >> 6;
    int lane = threadIdx.x & 63;
    int node = blockIdx.x * 4 + w;
    if (node >= N) return;
    int s = offs[node], e = offs[node + 1];

    const bool isv = lane >= 32;
    const int  fb  = (lane & 31) * 8;
    const unsigned short* base = mv + (isv ? 256 : 0) + fb;

    float acc[8];
    #pragma unroll
    for (int q = 0; q < 8; ++q) acc[q] = 0.f;

    int j = s;
    for (; j + 3 < e; j += 4) {
        i32x4 r0 = __builtin_nontemporal_load(&rec[j]);
        i32x4 r1 = __builtin_nontemporal_load(&rec[j+1]);
        i32x4 r2 = __builtin_nontemporal_load(&rec[j+2]);
        i32x4 r3 = __builtin_nontemporal_load(&rec[j+3]);
        ushort8v p0 = *(const ushort8v*)(base + (size_t)r0[0] * 512);
        ushort8v p1 = *(const ushort8v*)(base + (size_t)r1[0] * 512);
        ushort8v p2 = *(const ushort8v*)(base + (size_t)r2[0] * 512);
        ushort8v p3 = *(const ushort8v*)(base + (size_t)r3[0] * 512);
        float a0 = __int_as_float(isv ? r0[2] : r0[1]);
        float a1 = __int_as_float(isv ? r1[2] : r1[1]);
        float a2 = __int_as_float(isv ? r2[2] : r2[1]);
        float a3 = __int_as_float(isv ? r3[2] : r3[1]);
        #pragma unroll
        for (int q = 0; q < 8; ++q) acc[q] += a0 * b2f(p0[q]);
        #pragma unroll
        for (int q = 0; q < 8; ++q) acc[q] += a1 * b2f(p1[q]);
        #pragma unroll
        for (int q = 0; q < 8; ++q) acc[q] += a2 * b2f(p2[q]);
        #pragma unroll
        for (int q = 0; q < 8; ++q) acc[q] += a3 * b2f(p3[q]);
    }
    for (; j < e; ++j) {
        i32x4 r0 = __builtin_nontemporal_load(&rec[j]);
        ushort8v p = *(const ushort8v*)(base + (size_t)r0[0] * 512);
        float a = __int_as_float(isv ? r0[2] : r0[1]);
        #pragma unroll
        for (int q = 0; q < 8; ++q) acc[q] += a * b2f(p[q]);
    }

    float* obase = out + (isv ? (size_t)N * F : 0) + (size_t)node * F + fb;
    f32x4 o0 = { acc[0], acc[1], acc[2], acc[3] };
    f32x4 o1 = { acc[4], acc[5], acc[6], acc[7] };
    __builtin_nontemporal_store(o0, (f32x4*)obase);
    __builtin_nontemporal_store(o1, (f32x4*)(obase + 4));
}

// ---------------------------------------------------------------------------
extern "C" void kernel_launch(void* const* d_in, const int* in_sizes, int n_in,
                              void* d_out, int out_size, void* d_ws, size_t ws_size,
                              hipStream_t stream)
{
    const float* mean = (const float*)d_in[0];
    const float* var  = (const float*)d_in[1];
    const float* Wm   = (const float*)d_in[2];
    const float* bm   = (const float*)d_in[3];
    const float* Wv   = (const float*)d_in[4];
    const float* bv   = (const float*)d_in[5];
    const int*   erow = (const int*)d_in[6];
    const int*   ecol = (const int*)d_in[7];
    const float* a0   = (const float*)d_in[8];
    const float* a1   = (const float*)d_in[9];

    const int N = in_sizes[0] / F;     // 100000
    const int E = in_sizes[6];         // 3200000

    uintptr_t p = (uintptr_t)d_ws;
    auto take = [&](size_t bytes) {
        uintptr_t r = (p + 255) & ~(uintptr_t)255;
        p = r + bytes;
        return (void*)r;
    };
    unsigned short* mv     = (unsigned short*)take((size_t)N * 512 * 2);
    i32x4*          rec    = (i32x4*)take((size_t)E * 16);
    int*            count  = (int*)take((size_t)N * 4);
    int*            offs   = (int*)take((size_t)(N + 1) * 4);
    int*            cursor = (int*)take((size_t)N * 4);
    int*            bsums  = (int*)take(1024 * 4);
    unsigned short* Wt     = (unsigned short*)take((size_t)2 * 8 * 256 * 32 * 2);

    const int SB = (N + 1023) / 1024;

    hipMemsetAsync(count, 0, (size_t)N * 4, stream);

    // CSR build first: its streaming traffic must not evict mv from L3.
    wprep_kernel<<<16, 256, 0, stream>>>(Wm, Wv, Wt);
    hist_kernel<<<(E + 255) / 256, 256, 0, stream>>>(erow, E, count);
    scan1_kernel<<<SB, 256, 0, stream>>>(count, N, offs, bsums);
    scan2_kernel<<<1, 128, 0, stream>>>(bsums, SB, offs, N);
    scan3_kernel<<<SB, 256, 0, stream>>>(offs, N, bsums);
    hipMemcpyAsync(cursor, offs, (size_t)N * 4, hipMemcpyDeviceToDevice, stream);
    fill_kernel<<<(E + 255) / 256, 256, 0, stream>>>(erow, ecol, a0, a1, E, cursor, rec);

    // Dense writes mv (L3-allocated) immediately before spmm consumes it.
    dense_kernel<<<(N + 63) / 64, 512, 0, stream>>>(mean, var, Wt, bm, bv, mv, N);

    spmm_kernel<<<(N + 3) / 4, 256, 0, stream>>>(offs, rec, mv, (float*)d_out, N);
}

// Round 4
// 925.680 us; speedup vs baseline: 1.0094x; 1.0094x over previous
//
#include <hip/hip_runtime.h>
#include <hip/hip_bf16.h>
#include <stdint.h>

#define F 256            // IN_F == OUT_F == 256
#define KSTEP 32

typedef short bhalf8 __attribute__((ext_vector_type(8)));
typedef unsigned short ushort8v __attribute__((ext_vector_type(8)));
typedef float f32x4 __attribute__((ext_vector_type(4)));
typedef int i32x4 __attribute__((ext_vector_type(4)));

__device__ __forceinline__ unsigned short f2b(float f) {
    union { float f; uint32_t u; } x; x.f = f;
    uint32_t u = x.u;
    return (unsigned short)((u + 0x7FFFu + ((u >> 16) & 1u)) >> 16);
}
__device__ __forceinline__ float b2f(unsigned short h) {
    union { uint32_t u; float f; } x; x.u = ((uint32_t)h) << 16;
    return x.f;
}

// ---------------------------------------------------------------------------
// W prep: f32 W[k][n] -> bf16, pre-tiled per K-step: Wt[sel][ks][n][kk]
// ---------------------------------------------------------------------------
__global__ __launch_bounds__(256) void wprep_kernel(
    const float* __restrict__ Wm, const float* __restrict__ Wv,
    unsigned short* __restrict__ Wt)
{
    int idx = blockIdx.x * 256 + threadIdx.x;   // 4096 = 2 sel * 8 ks * 256 n
    int sel = idx >> 11;
    int ks  = (idx >> 8) & 7;
    int n   = idx & 255;
    const float* W = sel ? Wv : Wm;
    unsigned short* dst = Wt + ((size_t)sel * 8 * 256 * 32) + ((size_t)(ks * 256 + n) * 32);
    #pragma unroll
    for (int kk = 0; kk < 32; ++kk)
        dst[kk] = f2b(W[(ks * 32 + kk) * 256 + n]);
}

// ---------------------------------------------------------------------------
// Dense: m' = elu(mean@Wm + bm) * att ;  v' = relu(var@Wv + bv) * att^2
// att = exp(-relu(var@Wv+bv)). Stored bf16 INTERLEAVED: mv[row][512].
// ---------------------------------------------------------------------------
__global__ __launch_bounds__(512) void dense_kernel(
    const float* __restrict__ mean, const float* __restrict__ var,
    const unsigned short* __restrict__ Wt,
    const float* __restrict__ bm, const float* __restrict__ bv,
    unsigned short* __restrict__ mv, int N)
{
    __shared__ unsigned short Asm[64][40];
    __shared__ unsigned short Asv[64][40];
    __shared__ unsigned short Bsm[256][40];
    __shared__ unsigned short Bsv[256][40];

    const int tid  = threadIdx.x;
    const int row0 = blockIdx.x * 64;
    const int lane = tid & 63;
    const int w    = tid >> 6;
    const int wr   = w >> 2;
    const int wc   = w & 3;
    const int lr   = lane & 15;
    const int lk   = lane >> 4;

    f32x4 accm[2][4], accv[2][4];
    #pragma unroll
    for (int i = 0; i < 2; ++i)
        #pragma unroll
        for (int j = 0; j < 4; ++j) { accm[i][j] = (f32x4)0.f; accv[i][j] = (f32x4)0.f; }

    const int srow = tid >> 3;
    const int skq  = (tid & 7) * 4;
    int sgrow = row0 + srow; if (sgrow >= N) sgrow = N - 1;

    const unsigned short* WtV = Wt + (size_t)8 * 256 * 32;

    for (int ks = 0; ks < F / KSTEP; ++ks) {
        const int k0 = ks * KSTEP;
        {
            const float4 am = *(const float4*)&mean[(size_t)sgrow * F + k0 + skq];
            const float4 av = *(const float4*)&var [(size_t)sgrow * F + k0 + skq];
            ushort4 um = { f2b(am.x), f2b(am.y), f2b(am.z), f2b(am.w) };
            ushort4 uv = { f2b(av.x), f2b(av.y), f2b(av.z), f2b(av.w) };
            *(ushort4*)&Asm[srow][skq] = um;
            *(ushort4*)&Asv[srow][skq] = uv;
        }
        {
            const unsigned short* sm = Wt  + (size_t)(ks * 256) * 32;
            const unsigned short* sv = WtV + (size_t)(ks * 256) * 32;
            #pragma unroll
            for (int h = 0; h < 2; ++h) {
                int c = tid + h * 512;
                int n = c >> 2, q = c & 3;
                *(ushort8v*)&Bsm[n][q * 8] = *(const ushort8v*)(sm + (size_t)n * 32 + q * 8);
                *(ushort8v*)&Bsv[n][q * 8] = *(const ushort8v*)(sv + (size_t)n * 32 + q * 8);
            }
        }
        __syncthreads();

        bhalf8 am0 = *(const bhalf8*)&Asm[wr*32 +  0 + lr][lk*8];
        bhalf8 am1 = *(const bhalf8*)&Asm[wr*32 + 16 + lr][lk*8];
        bhalf8 av0 = *(const bhalf8*)&Asv[wr*32 +  0 + lr][lk*8];
        bhalf8 av1 = *(const bhalf8*)&Asv[wr*32 + 16 + lr][lk*8];
        #pragma unroll
        for (int ct = 0; ct < 4; ++ct) {
            bhalf8 bmf = *(const bhalf8*)&Bsm[wc*64 + ct*16 + lr][lk*8];
            bhalf8 bvf = *(const bhalf8*)&Bsv[wc*64 + ct*16 + lr][lk*8];
            accm[0][ct] = __builtin_amdgcn_mfma_f32_16x16x32_bf16(am0, bmf, accm[0][ct], 0, 0, 0);
            accm[1][ct] = __builtin_amdgcn_mfma_f32_16x16x32_bf16(am1, bmf, accm[1][ct], 0, 0, 0);
            accv[0][ct] = __builtin_amdgcn_mfma_f32_16x16x32_bf16(av0, bvf, accv[0][ct], 0, 0, 0);
            accv[1][ct] = __builtin_amdgcn_mfma_f32_16x16x32_bf16(av1, bvf, accv[1][ct], 0, 0, 0);
        }
        __syncthreads();
    }

    #pragma unroll
    for (int rt = 0; rt < 2; ++rt) {
        #pragma unroll
        for (int ct = 0; ct < 4; ++ct) {
            const int col = wc*64 + ct*16 + lr;
            const float bmc = bm[col], bvc = bv[col];
            #pragma unroll
            for (int q = 0; q < 4; ++q) {
                int grow = row0 + wr*32 + rt*16 + lk*4 + q;
                if (grow < N) {
                    float mp = accm[rt][ct][q] + bmc;
                    float vp = accv[rt][ct][q] + bvc;
                    float me = mp > 0.f ? mp : (__expf(mp) - 1.f);
                    float vr = vp > 0.f ? vp : 0.f;
                    float att = __expf(-vr);
                    mv[(size_t)grow * 512 + col]       = f2b(me * att);
                    mv[(size_t)grow * 512 + 256 + col] = f2b(vr * att * att);
                }
            }
        }
    }
}

// ---------------------------------------------------------------------------
// CSR build
// ---------------------------------------------------------------------------
__global__ void hist_kernel(const int* __restrict__ row, int E, int* __restrict__ count) {
    int i = blockIdx.x * blockDim.x + threadIdx.x;
    if (i < E) {
        int r = __builtin_nontemporal_load(&row[i]);
        atomicAdd(&count[r], 1);
    }
}

__global__ __launch_bounds__(256) void scan1_kernel(const int* __restrict__ count, int N,
                                                    int* __restrict__ offs, int* __restrict__ bsums)
{
    __shared__ int sd[256];
    int t  = threadIdx.x;
    int gi = blockIdx.x * 1024 + t * 4;
    int c[4];
    #pragma unroll
    for (int q = 0; q < 4; ++q) c[q] = (gi + q < N) ? count[gi + q] : 0;
    int s = c[0] + c[1] + c[2] + c[3];
    sd[t] = s; __syncthreads();
    int acc = s;
    for (int off = 1; off < 256; off <<= 1) {
        int u = (t >= off) ? sd[t - off] : 0;
        __syncthreads();
        acc += u; sd[t] = acc;
        __syncthreads();
    }
    int run = acc - s;
    #pragma unroll
    for (int q = 0; q < 4; ++q) { if (gi + q < N) offs[gi + q] = run; run += c[q]; }
    if (t == 255) bsums[blockIdx.x] = acc;
}

__global__ __launch_bounds__(128) void scan2_kernel(int* __restrict__ bsums, int SB,
                                                    int* __restrict__ offs, int N)
{
    __shared__ int sd[128];
    int t = threadIdx.x;
    int v = (t < SB) ? bsums[t] : 0;
    sd[t] = v; __syncthreads();
    int acc = v;
    for (int off = 1; off < 128; off <<= 1) {
        int u = (t >= off) ? sd[t - off] : 0;
        __syncthreads();
        acc += u; sd[t] = acc;
        __syncthreads();
    }
    if (t < SB) bsums[t] = acc - v;
    if (t == 127) offs[N] = sd[127];
}

__global__ __launch_bounds__(256) void scan3_kernel(int* __restrict__ offs, int N,
                                                    const int* __restrict__ bsums)
{
    int b  = bsums[blockIdx.x];
    int gi = blockIdx.x * 1024 + threadIdx.x * 4;
    #pragma unroll
    for (int q = 0; q < 4; ++q) if (gi + q < N) offs[gi + q] += b;
}

__global__ void fill_kernel(const int* __restrict__ row, const int* __restrict__ col,
                            const float* __restrict__ a0, const float* __restrict__ a1,
                            int E, int* __restrict__ cursor, i32x4* __restrict__ rec)
{
    int i = blockIdx.x * blockDim.x + threadIdx.x;
    if (i < E) {
        int   r  = __builtin_nontemporal_load(&row[i]);
        int   c  = __builtin_nontemporal_load(&col[i]);
        float v0 = __builtin_nontemporal_load(&a0[i]);
        float v1 = __builtin_nontemporal_load(&a1[i]);
        int pos = atomicAdd(&cursor[r], 1);
        i32x4 rc;
        rc[0] = c;
        rc[1] = __float_as_int(v0);
        rc[2] = __float_as_int(v1);
        rc[3] = 0;
        rec[pos] = rc;
    }
}

// ---------------------------------------------------------------------------
// Fused SpMM: 1 wave per node; 8-deep gather batches with records for the
// NEXT batch prefetched while the current batch's gathers are in flight.
// lanes 0-31: m half, lanes 32-63: v half (8 feats each, 16B gather/lane).
// ---------------------------------------------------------------------------
__global__ __launch_bounds__(256) void spmm_kernel(
    const int* __restrict__ offs, const int* __restrict__ rec,
    const unsigned short* __restrict__ mv,
    float* __restrict__ out, int N)
{
    int w    = threadIdx.x >> 6;
    int lane = threadIdx.x & 63;
    int node = blockIdx.x * 4 + w;
    if (node >= N) return;
    int s = offs[node], e = offs[node + 1];

    const bool isv = lane >= 32;
    const int  fb  = (lane & 31) * 8;
    const unsigned short* base = mv + (isv ? 256 : 0) + fb;
    const int woff = isv ? 2 : 1;

    float acc[8];
    #pragma unroll
    for (int q = 0; q < 8; ++q) acc[q] = 0.f;

    const int cnt = e - s;
    const int nb  = cnt >> 3;               // full 8-edge batches
    const int* rp = rec + (size_t)s * 4;

    if (nb > 0) {
        int   c[8];
        float wt[8];
        #pragma unroll
        for (int q = 0; q < 8; ++q) {
            c[q]  = __builtin_nontemporal_load(rp + q * 4);
            wt[q] = __int_as_float(__builtin_nontemporal_load(rp + q * 4 + woff));
        }
        for (int b = 0; b < nb; ++b) {
            // issue 8 independent gathers
            ushort8v p[8];
            #pragma unroll
            for (int q = 0; q < 8; ++q)
                p[q] = *(const ushort8v*)(base + (size_t)c[q] * 512);
            // prefetch next batch's records (independent of gathers)
            int   cn[8];
            float wn[8];
            if (b + 1 < nb) {
                const int* rn = rp + 32;
                #pragma unroll
                for (int q = 0; q < 8; ++q) {
                    cn[q] = __builtin_nontemporal_load(rn + q * 4);
                    wn[q] = __int_as_float(__builtin_nontemporal_load(rn + q * 4 + woff));
                }
            }
            // accumulate
            #pragma unroll
            for (int q = 0; q < 8; ++q) {
                #pragma unroll
                for (int t = 0; t < 8; ++t) acc[t] += wt[q] * b2f(p[q][t]);
            }
            #pragma unroll
            for (int q = 0; q < 8; ++q) { c[q] = cn[q]; wt[q] = wn[q]; }
            rp += 32;
        }
    }
    // tail
    for (int j = s + nb * 8; j < e; ++j) {
        const int* rj = rec + (size_t)j * 4;
        int   cc = rj[0];
        float a  = __int_as_float(rj[woff]);
        ushort8v p = *(const ushort8v*)(base + (size_t)cc * 512);
        #pragma unroll
        for (int t = 0; t < 8; ++t) acc[t] += a * b2f(p[t]);
    }

    float* obase = out + (isv ? (size_t)N * F : 0) + (size_t)node * F + fb;
    float4 o0 = { acc[0], acc[1], acc[2], acc[3] };
    float4 o1 = { acc[4], acc[5], acc[6], acc[7] };
    *(float4*)obase       = o0;
    *(float4*)(obase + 4) = o1;
}

// ---------------------------------------------------------------------------
extern "C" void kernel_launch(void* const* d_in, const int* in_sizes, int n_in,
                              void* d_out, int out_size, void* d_ws, size_t ws_size,
                              hipStream_t stream)
{
    const float* mean = (const float*)d_in[0];
    const float* var  = (const float*)d_in[1];
    const float* Wm   = (const float*)d_in[2];
    const float* bm   = (const float*)d_in[3];
    const float* Wv   = (const float*)d_in[4];
    const float* bv   = (const float*)d_in[5];
    const int*   erow = (const int*)d_in[6];
    const int*   ecol = (const int*)d_in[7];
    const float* a0   = (const float*)d_in[8];
    const float* a1   = (const float*)d_in[9];

    const int N = in_sizes[0] / F;     // 100000
    const int E = in_sizes[6];         // 3200000

    uintptr_t p = (uintptr_t)d_ws;
    auto take = [&](size_t bytes) {
        uintptr_t r = (p + 255) & ~(uintptr_t)255;
        p = r + bytes;
        return (void*)r;
    };
    unsigned short* mv     = (unsigned short*)take((size_t)N * 512 * 2);
    int*            rec    = (int*)take((size_t)E * 16);
    int*            count  = (int*)take((size_t)N * 4);
    int*            offs   = (int*)take((size_t)(N + 1) * 4);
    int*            cursor = (int*)take((size_t)N * 4);
    int*            bsums  = (int*)take(1024 * 4);
    unsigned short* Wt     = (unsigned short*)take((size_t)2 * 8 * 256 * 32 * 2);

    const int SB = (N + 1023) / 1024;

    hipMemsetAsync(count, 0, (size_t)N * 4, stream);

    wprep_kernel<<<16, 256, 0, stream>>>(Wm, Wv, Wt);
    dense_kernel<<<(N + 63) / 64, 512, 0, stream>>>(mean, var, Wt, bm, bv, mv, N);

    hist_kernel<<<(E + 255) / 256, 256, 0, stream>>>(erow, E, count);
    scan1_kernel<<<SB, 256, 0, stream>>>(count, N, offs, bsums);
    scan2_kernel<<<1, 128, 0, stream>>>(bsums, SB, offs, N);
    scan3_kernel<<<SB, 256, 0, stream>>>(offs, N, bsums);
    hipMemcpyAsync(cursor, offs, (size_t)N * 4, hipMemcpyDeviceToDevice, stream);
    fill_kernel<<<(E + 255) / 256, 256, 0, stream>>>(erow, ecol, a0, a1, E, cursor, (i32x4*)rec);

    spmm_kernel<<<(N + 3) / 4, 256, 0, stream>>>(offs, rec, mv, (float*)d_out, N);
}